// Round 1
// baseline (502.255 us; speedup 1.0000x reference)
//
#include <hip/hip_runtime.h>
#include <hip/hip_bf16.h>
#include <stdint.h>

#define BB 4
#define TT 2048
#define DD 1024
#define HH 16
#define HDD 64
#define MTOK (BB*TT)

typedef __bf16 bf16x8 __attribute__((ext_vector_type(8)));
typedef float f32x4 __attribute__((ext_vector_type(4)));

__device__ __forceinline__ uint16_t f2bf(float f){
  uint32_t u = __float_as_uint(f);
  u += 0x7fffu + ((u >> 16) & 1u);
  return (uint16_t)(u >> 16);
}
__device__ __forceinline__ float bf2f(uint16_t h){ return __uint_as_float(((uint32_t)h) << 16); }
__device__ __forceinline__ float sigm(float z){ return 1.f / (1.f + __expf(-z)); }

// ---------------- f32 -> bf16 cast, 4 elems/thread ----------------
__global__ void cvt_kernel(const float* __restrict__ in, uint16_t* __restrict__ out, int n4){
  int i = blockIdx.x * blockDim.x + threadIdx.x;
  if (i < n4){
    float4 v = ((const float4*)in)[i];
    ushort4 o;
    o.x = f2bf(v.x); o.y = f2bf(v.y); o.z = f2bf(v.z); o.w = f2bf(v.w);
    ((ushort4*)out)[i] = o;
  }
}

// ---------------- bf16 MFMA GEMM: Y = act(X @ W^T) ----------------
// X: [M][K] bf16 row-major, W: [N][K] bf16 row-major (both K-contiguous).
// 128x128 tile, BK=32, 256 threads (4 waves, 2x2 wave grid, 64x64 per wave).
// ACT: 0=none, 1=silu, 2=sigmoid. BF16OUT selects output buffer.
template<int ACT, int BF16OUT>
__global__ __launch_bounds__(256) void gemm_bt(
    const uint16_t* __restrict__ X, const uint16_t* __restrict__ W,
    uint16_t* __restrict__ Yb, float* __restrict__ Yf, int M, int N, int K)
{
  // LDS tiles: [kb (4)][row (128)] of 16B (8 bf16) segments
  __shared__ uint4 lA[512];
  __shared__ uint4 lB[512];

  const int tid = threadIdx.x;
  const int m0 = blockIdx.y * 128;
  const int n0 = blockIdx.x * 128;
  const int l = tid & 63, w = tid >> 6;
  const int wr = w >> 1, wc = w & 1;
  const int g = l >> 4, r16 = l & 15;

  // staging: 512 segments per tile, 2 per thread; consecutive threads cover 64B of a row
  const int kb0 = tid & 3,         row0 = tid >> 2;
  const int kb1 = (tid + 256) & 3, row1 = (tid + 256) >> 2;

  const uint16_t* Xp0 = X + (size_t)(m0 + row0) * K + kb0 * 8;
  const uint16_t* Xp1 = X + (size_t)(m0 + row1) * K + kb1 * 8;
  const uint16_t* Wp0 = W + (size_t)(n0 + row0) * K + kb0 * 8;
  const uint16_t* Wp1 = W + (size_t)(n0 + row1) * K + kb1 * 8;

  f32x4 acc[4][4];
  #pragma unroll
  for (int i = 0; i < 4; i++)
    #pragma unroll
    for (int j = 0; j < 4; j++) acc[i][j] = (f32x4){0.f, 0.f, 0.f, 0.f};

  // prologue: load tile 0
  uint4 a0 = *(const uint4*)(Xp0);
  uint4 a1 = *(const uint4*)(Xp1);
  uint4 b0 = *(const uint4*)(Wp0);
  uint4 b1 = *(const uint4*)(Wp1);

  for (int kt = 0; kt < K; kt += 32){
    __syncthreads();  // WAR: prior iteration's LDS reads done
    lA[kb0 * 128 + row0] = a0; lA[kb1 * 128 + row1] = a1;
    lB[kb0 * 128 + row0] = b0; lB[kb1 * 128 + row1] = b1;
    __syncthreads();

    if (kt + 32 < K){  // prefetch next tile while MFMAs run
      a0 = *(const uint4*)(Xp0 + kt + 32);
      a1 = *(const uint4*)(Xp1 + kt + 32);
      b0 = *(const uint4*)(Wp0 + kt + 32);
      b1 = *(const uint4*)(Wp1 + kt + 32);
    }

    bf16x8 af[4], bfr[4];
    #pragma unroll
    for (int mi = 0; mi < 4; mi++)
      af[mi] = __builtin_bit_cast(bf16x8, lA[g * 128 + wr * 64 + mi * 16 + r16]);
    #pragma unroll
    for (int ni = 0; ni < 4; ni++)
      bfr[ni] = __builtin_bit_cast(bf16x8, lB[g * 128 + wc * 64 + ni * 16 + r16]);

    #pragma unroll
    for (int mi = 0; mi < 4; mi++)
      #pragma unroll
      for (int ni = 0; ni < 4; ni++)
        acc[mi][ni] = __builtin_amdgcn_mfma_f32_16x16x32_bf16(af[mi], bfr[ni], acc[mi][ni], 0, 0, 0);
  }

  // epilogue: C/D layout col=lane&15, row=(lane>>4)*4+reg  [m89-verified]
  #pragma unroll
  for (int mi = 0; mi < 4; mi++){
    #pragma unroll
    for (int ni = 0; ni < 4; ni++){
      int rg = m0 + wr * 64 + mi * 16 + g * 4;
      int cg = n0 + wc * 64 + ni * 16 + r16;
      #pragma unroll
      for (int r = 0; r < 4; r++){
        float v = acc[mi][ni][r];
        if (ACT == 1) v = v * (1.f / (1.f + __expf(-v)));
        else if (ACT == 2) v = 1.f / (1.f + __expf(-v));
        if (BF16OUT) Yb[(size_t)(rg + r) * N + cg] = f2bf(v);
        else         Yf[(size_t)(rg + r) * N + cg] = v;
      }
    }
  }
}

// ---------------- small projections: beta/fd/sd = sigmoid(x @ W^T + b) ----------------
// one wave per token; sc layout [3][B][H][T]
__global__ __launch_bounds__(256) void small_proj(
    const float* __restrict__ x,
    const float* __restrict__ Wb, const float* __restrict__ Wfd, const float* __restrict__ bfd,
    const float* __restrict__ Wsd, const float* __restrict__ bsd,
    float* __restrict__ sc)
{
  int token = blockIdx.x * 4 + (threadIdx.x >> 6);
  int lane = threadIdx.x & 63;
  const float4* xr = (const float4*)(x + (size_t)token * DD);
  float4 xv[4];
  #pragma unroll
  for (int i = 0; i < 4; i++) xv[i] = xr[lane * 4 + i];
  int b = token / TT, t = token % TT;

  for (int j = 0; j < 48; j++){
    int grp = j >> 4, h = j & 15;
    const float* wrow;
    float bias;
    if (grp == 0){ wrow = Wb  + (size_t)h * DD; bias = 0.f; }
    else if (grp == 1){ wrow = Wfd + (size_t)h * DD; bias = bfd[h]; }
    else { wrow = Wsd + (size_t)h * DD; bias = bsd[h]; }
    const float4* wr4 = (const float4*)wrow;
    float s = 0.f;
    #pragma unroll
    for (int i = 0; i < 4; i++){
      float4 wv = wr4[lane * 4 + i];
      s += xv[i].x * wv.x + xv[i].y * wv.y + xv[i].z * wv.z + xv[i].w * wv.w;
    }
    #pragma unroll
    for (int off = 32; off; off >>= 1) s += __shfl_xor(s, off);
    if (lane == 0){
      sc[(((size_t)grp * BB + b) * HH + h) * TT + t] = sigm(s + bias);
    }
  }
}

// ---------------- sequential scan, fused with o*g, bf16 out ----------------
// one block (1 wave) per (b,h); lane = channel dc in [0,64)
__global__ __launch_bounds__(64) void scan_kernel(
    const uint16_t* __restrict__ qb, const uint16_t* __restrict__ kb,
    const uint16_t* __restrict__ vb, const uint16_t* __restrict__ gb,
    const float* __restrict__ sc, uint16_t* __restrict__ og)
{
  int bh = blockIdx.x;
  int b = bh >> 4, h = bh & 15;
  int dc = threadIdx.x;
  size_t base = (size_t)b * TT * DD + h * HDD + dc;
  const float* bet = sc + (((size_t)0 * BB + b) * HH + h) * TT;
  const float* fdp = sc + (((size_t)1 * BB + b) * HH + h) * TT;
  const float* sdp = sc + (((size_t)2 * BB + b) * HH + h) * TT;

  float sf = 0.f, ss = 0.f;
  #pragma unroll 8
  for (int t = 0; t < TT; t++){
    size_t idx = base + (size_t)t * DD;
    float qv = bf2f(qb[idx]);
    float kv = bf2f(kb[idx]);
    float vv = bf2f(vb[idx]);
    float gv = bf2f(gb[idx]);
    float btv = bet[t], ftv = fdp[t], stv = sdp[t];
    sf *= ftv; ss *= stv;
    float o = 0.5f * qv * (sf + ss);
    float u = btv * kv * vv;
    sf += u; ss += u;
    float nf = sf + 0.05f * ss;
    ss = ss + 0.05f * sf;
    sf = nf;
    og[idx] = f2bf(o * gv);
  }
}

extern "C" void kernel_launch(void* const* d_in, const int* in_sizes, int n_in,
                              void* d_out, int out_size, void* d_ws, size_t ws_size,
                              hipStream_t stream)
{
  const float* x   = (const float*)d_in[0];
  const float* Wq  = (const float*)d_in[1];
  const float* Wk  = (const float*)d_in[2];
  const float* Wv  = (const float*)d_in[3];
  const float* Wo  = (const float*)d_in[4];
  const float* Wb  = (const float*)d_in[5];
  const float* Wfd = (const float*)d_in[6];
  const float* bfd = (const float*)d_in[7];
  const float* Wsd = (const float*)d_in[8];
  const float* bsd = (const float*)d_in[9];
  const float* Wg  = (const float*)d_in[10];
  float* out = (float*)d_out;

  char* ws = (char*)d_ws;
  size_t off = 0;
  auto alloc = [&](size_t bytes) -> void* {
    void* p = ws + off;
    off += (bytes + 255) & ~(size_t)255;
    return p;
  };

  uint16_t* xb  = (uint16_t*)alloc((size_t)MTOK * DD * 2);
  uint16_t* wqb = (uint16_t*)alloc((size_t)DD * DD * 2);
  uint16_t* wkb = (uint16_t*)alloc((size_t)DD * DD * 2);
  uint16_t* wvb = (uint16_t*)alloc((size_t)DD * DD * 2);
  uint16_t* wgb = (uint16_t*)alloc((size_t)DD * DD * 2);
  uint16_t* wob = (uint16_t*)alloc((size_t)DD * DD * 2);
  uint16_t* qb  = (uint16_t*)alloc((size_t)MTOK * DD * 2);
  uint16_t* kbuf= (uint16_t*)alloc((size_t)MTOK * DD * 2);
  uint16_t* vbuf= (uint16_t*)alloc((size_t)MTOK * DD * 2);
  uint16_t* gbuf= (uint16_t*)alloc((size_t)MTOK * DD * 2);
  uint16_t* ogb = (uint16_t*)alloc((size_t)MTOK * DD * 2);
  float* sc     = (float*)alloc((size_t)3 * BB * HH * TT * 4);

  // casts
  int n4x = MTOK * DD / 4;
  cvt_kernel<<<(n4x + 255) / 256, 256, 0, stream>>>(x, xb, n4x);
  int n4w = DD * DD / 4;
  cvt_kernel<<<(n4w + 255) / 256, 256, 0, stream>>>(Wq, wqb, n4w);
  cvt_kernel<<<(n4w + 255) / 256, 256, 0, stream>>>(Wk, wkb, n4w);
  cvt_kernel<<<(n4w + 255) / 256, 256, 0, stream>>>(Wv, wvb, n4w);
  cvt_kernel<<<(n4w + 255) / 256, 256, 0, stream>>>(Wg, wgb, n4w);
  cvt_kernel<<<(n4w + 255) / 256, 256, 0, stream>>>(Wo, wob, n4w);

  dim3 gg(DD / 128, MTOK / 128);
  gemm_bt<1, 1><<<gg, 256, 0, stream>>>(xb, wqb, qb,   nullptr, MTOK, DD, DD);  // q = silu
  gemm_bt<1, 1><<<gg, 256, 0, stream>>>(xb, wkb, kbuf, nullptr, MTOK, DD, DD);  // k = silu
  gemm_bt<1, 1><<<gg, 256, 0, stream>>>(xb, wvb, vbuf, nullptr, MTOK, DD, DD);  // v = silu
  gemm_bt<2, 1><<<gg, 256, 0, stream>>>(xb, wgb, gbuf, nullptr, MTOK, DD, DD);  // g = sigmoid

  small_proj<<<MTOK / 4, 256, 0, stream>>>(x, Wb, Wfd, bfd, Wsd, bsd, sc);

  scan_kernel<<<BB * HH, 64, 0, stream>>>(qb, kbuf, vbuf, gbuf, sc, ogb);

  gemm_bt<0, 0><<<gg, 256, 0, stream>>>(ogb, wob, nullptr, out, MTOK, DD, DD);  // out = (o*g) @ Wo^T
}

// Round 2
// 274.236 us; speedup vs baseline: 1.8315x; 1.8315x over previous
//
#include <hip/hip_runtime.h>
#include <hip/hip_bf16.h>
#include <stdint.h>

#define BB 4
#define TT 2048
#define DD 1024
#define HH 16
#define MTOK (BB*TT)
#define NQ 4096            // q|k|v|g concat width
#define TC 32              // scan chunk length
#define NC (TT/TC)         // 64 chunks
#define BH (BB*HH)         // 64

typedef __bf16 bf16x8 __attribute__((ext_vector_type(8)));
typedef float f32x4 __attribute__((ext_vector_type(4)));

__device__ __forceinline__ uint16_t f2bf(float f){
  uint32_t u = __float_as_uint(f);
  u += 0x7fffu + ((u >> 16) & 1u);
  return (uint16_t)(u >> 16);
}
__device__ __forceinline__ float bf2f(uint32_t h){ return __uint_as_float(h << 16); }
__device__ __forceinline__ float sigm(float z){ return 1.f / (1.f + __expf(-z)); }

__device__ __forceinline__ void gll16(const uint16_t* src, uint16_t* dst){
  __builtin_amdgcn_global_load_lds(
      (const __attribute__((address_space(1))) void*)src,
      (__attribute__((address_space(3))) void*)dst, 16, 0, 0);
}

// ---------------- f32 -> bf16 cast ----------------
__global__ void cvt_kernel(const float* __restrict__ in, uint16_t* __restrict__ out, int n4){
  int i = blockIdx.x * blockDim.x + threadIdx.x;
  if (i < n4){
    float4 v = ((const float4*)in)[i];
    ushort4 o;
    o.x = f2bf(v.x); o.y = f2bf(v.y); o.z = f2bf(v.z); o.w = f2bf(v.w);
    ((ushort4*)out)[i] = o;
  }
}

// ---------------- bf16 MFMA GEMM (m97 structure): Y = act(X @ W^T) ----------------
// X:[M][K], W:[N][K] bf16 row-major. 128x128 tile, BK=32, 256 thr (2x2 waves).
// global_load_lds width-16: linear LDS dest, pre-swizzled global source (rule #21);
// slot s holds logical (row=s>>2, kb=(s&3)^p(row)), p(row)=(row>>1)&3 -> conflict-free b128 reads.
// ACT: 0 none, 3 = qkvg mode (col<3072 silu, else sigmoid). BF16OUT picks output buffer.
template<int ACT, int BF16OUT>
__global__ __launch_bounds__(256) void gemm_bt(
    const uint16_t* __restrict__ X, const uint16_t* __restrict__ W,
    uint16_t* __restrict__ Yb, float* __restrict__ Yf, int M, int N, int K)
{
  __shared__ __align__(16) uint16_t lA[128*32];
  __shared__ __align__(16) uint16_t lB[128*32];
  const int tid = threadIdx.x;
  const int m0 = blockIdx.y * 128, n0 = blockIdx.x * 128;
  const int l = tid & 63, w = tid >> 6;
  const int wr = w >> 1, wc = w & 1;
  const int g = l >> 4, r16 = l & 15;
  const int p = (r16 >> 1) & 3;

  // staging: wave w owns slots [w*128, w*128+128), two gll calls of 64 slots
  const int s0 = w * 128 + l, s1 = s0 + 64;
  const int r0 = s0 >> 2, c0 = (((s0 & 3) ^ ((r0 >> 1) & 3)) << 3);
  const int r1 = s1 >> 2, c1 = (((s1 & 3) ^ ((r1 >> 1) & 3)) << 3);
  const uint16_t* aS0 = X + (size_t)(m0 + r0) * K + c0;
  const uint16_t* aS1 = X + (size_t)(m0 + r1) * K + c1;
  const uint16_t* bS0 = W + (size_t)(n0 + r0) * K + c0;
  const uint16_t* bS1 = W + (size_t)(n0 + r1) * K + c1;
  uint16_t* dA0 = lA + w * 1024; uint16_t* dA1 = dA0 + 512;
  uint16_t* dB0 = lB + w * 1024; uint16_t* dB1 = dB0 + 512;

  int roA[4], roB[4];
  #pragma unroll
  for (int i = 0; i < 4; i++){
    roA[i] = (wr * 64 + i * 16 + r16) * 32 + ((g ^ p) << 3);
    roB[i] = (wc * 64 + i * 16 + r16) * 32 + ((g ^ p) << 3);
  }

  f32x4 acc[4][4];
  #pragma unroll
  for (int i = 0; i < 4; i++)
    #pragma unroll
    for (int j = 0; j < 4; j++) acc[i][j] = (f32x4){0.f, 0.f, 0.f, 0.f};

  for (int kt = 0; kt < K; kt += 32){
    __syncthreads();                 // WAR: prior reads done
    gll16(aS0 + kt, dA0); gll16(aS1 + kt, dA1);
    gll16(bS0 + kt, dB0); gll16(bS1 + kt, dB1);
    __syncthreads();                 // vmcnt(0) drain -> LDS valid

    bf16x8 af[4], bw[4];
    #pragma unroll
    for (int mi = 0; mi < 4; mi++) af[mi] = *(const bf16x8*)(lA + roA[mi]);
    #pragma unroll
    for (int ni = 0; ni < 4; ni++) bw[ni] = *(const bf16x8*)(lB + roB[ni]);

    #pragma unroll
    for (int mi = 0; mi < 4; mi++)
      #pragma unroll
      for (int ni = 0; ni < 4; ni++)
        acc[mi][ni] = __builtin_amdgcn_mfma_f32_16x16x32_bf16(af[mi], bw[ni], acc[mi][ni], 0, 0, 0);
  }

  // C/D layout: col=lane&15, row=(lane>>4)*4+reg  [m89-verified]
  const bool dosig  = (ACT == 3) && (n0 >= 3 * DD);
  const bool dosilu = (ACT == 3) && (n0 < 3 * DD);
  #pragma unroll
  for (int mi = 0; mi < 4; mi++){
    #pragma unroll
    for (int ni = 0; ni < 4; ni++){
      int rg = m0 + wr * 64 + mi * 16 + g * 4;
      int cg = n0 + wc * 64 + ni * 16 + r16;
      #pragma unroll
      for (int r = 0; r < 4; r++){
        float v = acc[mi][ni][r];
        if (dosilu) v = v * sigm(v);
        else if (dosig) v = sigm(v);
        if (BF16OUT) Yb[(size_t)(rg + r) * N + cg] = f2bf(v);
        else         Yf[(size_t)(rg + r) * N + cg] = v;
      }
    }
  }
}

// ---------------- small projections: beta/fd/sd = sigmoid(x @ W^T + b), [3][B][H][T] ----------------
__global__ __launch_bounds__(256) void small_proj(
    const float* __restrict__ x,
    const float* __restrict__ Wb, const float* __restrict__ Wfd, const float* __restrict__ bfd,
    const float* __restrict__ Wsd, const float* __restrict__ bsd,
    float* __restrict__ sc)
{
  int token = blockIdx.x * 4 + (threadIdx.x >> 6);
  int lane = threadIdx.x & 63;
  const float4* xr = (const float4*)(x + (size_t)token * DD);
  float4 xv[4];
  #pragma unroll
  for (int i = 0; i < 4; i++) xv[i] = xr[lane * 4 + i];
  int b = token / TT, t = token % TT;

  for (int j = 0; j < 48; j++){
    int grp = j >> 4, h = j & 15;
    const float* wrow;
    float bias;
    if (grp == 0){ wrow = Wb  + (size_t)h * DD; bias = 0.f; }
    else if (grp == 1){ wrow = Wfd + (size_t)h * DD; bias = bfd[h]; }
    else { wrow = Wsd + (size_t)h * DD; bias = bsd[h]; }
    const float4* wr4 = (const float4*)wrow;
    float s = 0.f;
    #pragma unroll
    for (int i = 0; i < 4; i++){
      float4 wv = wr4[lane * 4 + i];
      s += xv[i].x * wv.x + xv[i].y * wv.y + xv[i].z * wv.z + xv[i].w * wv.w;
    }
    #pragma unroll
    for (int off = 32; off; off >>= 1) s += __shfl_xor(s, off);
    if (lane == 0) sc[(((size_t)grp * BB + b) * HH + h) * TT + t] = sigm(s + bias);
  }
}

// ---------------- chunked scan ----------------
// step: [sf,ss]' = M_t [sf,ss] + 1.05*u_t*[1,1],  M_t = [[f,.05s],[.05f,s]]
// lane mapping (A/C): h = h0 + (l>>5), channel pair c2 = l&31 -> channels 2*c2, 2*c2+1

// Pass A: per (chunk j, head-pair hp): zero-entry local end state L + chunk matrix P
__global__ __launch_bounds__(64) void scan_partA(
    const uint16_t* __restrict__ qkvg, const float* __restrict__ sc,
    float2* __restrict__ Lst, float4* __restrict__ Pm)
{
  int j = blockIdx.x, hp = blockIdx.y;
  int b = hp >> 3, h0 = (hp & 7) * 2;
  int l = threadIdx.x;
  int h = h0 + (l >> 5), c2 = l & 31;
  int bh = b * HH + h;
  const uint16_t* kp = qkvg + ((size_t)(b * TT + j * TC)) * NQ + DD + h * 64 + c2 * 2;
  const uint16_t* vp = kp + DD;
  const float* bet = sc + ((size_t)(0 * BB + b) * HH + h) * TT + j * TC;
  const float* fdp = sc + ((size_t)(1 * BB + b) * HH + h) * TT + j * TC;
  const float* sdp = sc + ((size_t)(2 * BB + b) * HH + h) * TT + j * TC;

  float sf0 = 0.f, ss0 = 0.f, sf1 = 0.f, ss1 = 0.f;
  float p00 = 1.f, p01 = 0.f, p10 = 0.f, p11 = 0.f;
  p11 = 1.f;
  #pragma unroll 4
  for (int t = 0; t < TC; t++){
    uint32_t kk = *(const uint32_t*)kp; kp += NQ;
    uint32_t vv = *(const uint32_t*)vp; vp += NQ;
    float k0 = bf2f(kk & 0xffff), k1 = bf2f(kk >> 16);
    float v0 = bf2f(vv & 0xffff), v1 = bf2f(vv >> 16);
    float btv = bet[t], f = fdp[t], s = sdp[t];
    float u0 = 1.05f * btv * k0 * v0, u1 = 1.05f * btv * k1 * v1;
    float bq = 0.05f * s, cq = 0.05f * f;
    float n0 = f * sf0 + bq * ss0 + u0, m0_ = cq * sf0 + s * ss0 + u0;
    float n1 = f * sf1 + bq * ss1 + u1, m1_ = cq * sf1 + s * ss1 + u1;
    sf0 = n0; ss0 = m0_; sf1 = n1; ss1 = m1_;
    float q00 = f * p00 + bq * p10, q01 = f * p01 + bq * p11;
    float q10 = cq * p00 + s * p10, q11 = cq * p01 + s * p11;
    p00 = q00; p01 = q01; p10 = q10; p11 = q11;
  }
  size_t base = ((size_t)bh * NC + j) * 2;
  Lst[(base + 0) * 32 + c2] = make_float2(sf0, sf1);
  Lst[(base + 1) * 32 + c2] = make_float2(ss0, ss1);
  if ((l & 31) == 0) Pm[(size_t)bh * NC + j] = make_float4(p00, p01, p10, p11);
}

// Pass B: sequential combine over chunks -> entry states E (float view: channel = dc)
__global__ __launch_bounds__(64) void scan_partB(
    const float* __restrict__ Lst, const float4* __restrict__ Pm, float* __restrict__ Est)
{
  int bh = blockIdx.x, dc = threadIdx.x;
  float xf = 0.f, xs = 0.f;
  for (int j = 0; j < NC; j++){
    size_t base = ((size_t)bh * NC + j) * 2;
    Est[(base + 0) * 64 + dc] = xf;
    Est[(base + 1) * 64 + dc] = xs;
    float4 P = Pm[(size_t)bh * NC + j];
    float lf = Lst[(base + 0) * 64 + dc], ls = Lst[(base + 1) * 64 + dc];
    float nf = P.x * xf + P.y * xs + lf;
    float ns = P.z * xf + P.w * xs + ls;
    xf = nf; xs = ns;
  }
}

// Pass C: replay chunk with correct entry state; write og = o*g (bf16)
__global__ __launch_bounds__(64) void scan_partC(
    const uint16_t* __restrict__ qkvg, const float* __restrict__ sc,
    const float2* __restrict__ Est, uint16_t* __restrict__ og)
{
  int j = blockIdx.x, hp = blockIdx.y;
  int b = hp >> 3, h0 = (hp & 7) * 2;
  int l = threadIdx.x;
  int h = h0 + (l >> 5), c2 = l & 31;
  int bh = b * HH + h;
  size_t base = ((size_t)bh * NC + j) * 2;
  float2 ef = Est[(base + 0) * 32 + c2];
  float2 es = Est[(base + 1) * 32 + c2];
  float sf0 = ef.x, sf1 = ef.y, ss0 = es.x, ss1 = es.y;

  const uint16_t* qp = qkvg + ((size_t)(b * TT + j * TC)) * NQ + h * 64 + c2 * 2;
  const uint16_t* kp = qp + DD;
  const uint16_t* vp = qp + 2 * DD;
  const uint16_t* gp = qp + 3 * DD;
  uint16_t* op = og + ((size_t)(b * TT + j * TC)) * DD + h * 64 + c2 * 2;
  const float* bet = sc + ((size_t)(0 * BB + b) * HH + h) * TT + j * TC;
  const float* fdp = sc + ((size_t)(1 * BB + b) * HH + h) * TT + j * TC;
  const float* sdp = sc + ((size_t)(2 * BB + b) * HH + h) * TT + j * TC;

  #pragma unroll 4
  for (int t = 0; t < TC; t++){
    uint32_t qq = *(const uint32_t*)qp; qp += NQ;
    uint32_t kk = *(const uint32_t*)kp; kp += NQ;
    uint32_t vv = *(const uint32_t*)vp; vp += NQ;
    uint32_t gg = *(const uint32_t*)gp; gp += NQ;
    float q0 = bf2f(qq & 0xffff), q1 = bf2f(qq >> 16);
    float k0 = bf2f(kk & 0xffff), k1 = bf2f(kk >> 16);
    float v0 = bf2f(vv & 0xffff), v1 = bf2f(vv >> 16);
    float g0 = bf2f(gg & 0xffff), g1 = bf2f(gg >> 16);
    float btv = bet[t], f = fdp[t], s = sdp[t];
    sf0 *= f; ss0 *= s; sf1 *= f; ss1 *= s;
    float o0 = 0.5f * q0 * (sf0 + ss0);
    float o1 = 0.5f * q1 * (sf1 + ss1);
    float u0 = btv * k0 * v0, u1 = btv * k1 * v1;
    sf0 += u0; ss0 += u0; sf1 += u1; ss1 += u1;
    float nf0 = sf0 + 0.05f * ss0, ns0 = ss0 + 0.05f * sf0;
    float nf1 = sf1 + 0.05f * ss1, ns1 = ss1 + 0.05f * sf1;
    sf0 = nf0; ss0 = ns0; sf1 = nf1; ss1 = ns1;
    uint32_t pack = (uint32_t)f2bf(o0 * g0) | ((uint32_t)f2bf(o1 * g1) << 16);
    *(uint32_t*)op = pack; op += DD;
  }
}

extern "C" void kernel_launch(void* const* d_in, const int* in_sizes, int n_in,
                              void* d_out, int out_size, void* d_ws, size_t ws_size,
                              hipStream_t stream)
{
  const float* x   = (const float*)d_in[0];
  const float* Wq  = (const float*)d_in[1];
  const float* Wk  = (const float*)d_in[2];
  const float* Wv  = (const float*)d_in[3];
  const float* Wo  = (const float*)d_in[4];
  const float* Wb  = (const float*)d_in[5];
  const float* Wfd = (const float*)d_in[6];
  const float* bfd = (const float*)d_in[7];
  const float* Wsd = (const float*)d_in[8];
  const float* bsd = (const float*)d_in[9];
  const float* Wg  = (const float*)d_in[10];
  float* out = (float*)d_out;

  char* ws = (char*)d_ws;
  size_t off = 0;
  auto alloc = [&](size_t bytes) -> void* {
    void* p = ws + off;
    off += (bytes + 255) & ~(size_t)255;
    return p;
  };

  uint16_t* xb   = (uint16_t*)alloc((size_t)MTOK * DD * 2);   // doubles as ogb after qkvg GEMM
  uint16_t* wcat = (uint16_t*)alloc((size_t)4 * DD * DD * 2); // Wq|Wk|Wv|Wg
  uint16_t* wob  = (uint16_t*)alloc((size_t)DD * DD * 2);
  uint16_t* qkvg = (uint16_t*)alloc((size_t)MTOK * NQ * 2);
  float*    sc   = (float*)alloc((size_t)3 * BB * HH * TT * 4);
  float2*   Lst  = (float2*)alloc((size_t)BH * NC * 2 * 32 * 8);
  float2*   Est  = (float2*)alloc((size_t)BH * NC * 2 * 32 * 8);
  float4*   Pm   = (float4*)alloc((size_t)BH * NC * 16);
  uint16_t* ogb  = xb;

  // casts
  int n4x = MTOK * DD / 4;
  cvt_kernel<<<(n4x + 255) / 256, 256, 0, stream>>>(x, xb, n4x);
  int n4w = DD * DD / 4;
  cvt_kernel<<<(n4w + 255) / 256, 256, 0, stream>>>(Wq, wcat + 0 * DD * DD, n4w);
  cvt_kernel<<<(n4w + 255) / 256, 256, 0, stream>>>(Wk, wcat + 1 * DD * DD, n4w);
  cvt_kernel<<<(n4w + 255) / 256, 256, 0, stream>>>(Wv, wcat + 2 * DD * DD, n4w);
  cvt_kernel<<<(n4w + 255) / 256, 256, 0, stream>>>(Wg, wcat + 3 * DD * DD, n4w);
  cvt_kernel<<<(n4w + 255) / 256, 256, 0, stream>>>(Wo, wob, n4w);

  small_proj<<<MTOK / 4, 256, 0, stream>>>(x, Wb, Wfd, bfd, Wsd, bsd, sc);

  // fused q|k|v|g GEMM: [8192,1024] @ [4096,1024]^T
  dim3 gq(NQ / 128, MTOK / 128);
  gemm_bt<3, 1><<<gq, 256, 0, stream>>>(xb, wcat, qkvg, nullptr, MTOK, NQ, DD);

  // chunked scan
  dim3 gs(NC, BH / 2);
  scan_partA<<<gs, 64, 0, stream>>>(qkvg, sc, Lst, Pm);
  scan_partB<<<BH, 64, 0, stream>>>((const float*)Lst, Pm, (float*)Est);
  scan_partC<<<gs, 64, 0, stream>>>(qkvg, sc, Est, ogb);

  // out = (o*g) @ Wo^T, fp32 out
  dim3 go(DD / 128, MTOK / 128);
  gemm_bt<0, 0><<<go, 256, 0, stream>>>(ogb, wob, nullptr, out, MTOK, DD, DD);
}